// Round 2
// baseline (914.244 us; speedup 1.0000x reference)
//
#include <hip/hip_runtime.h>
#include <cstdint>
#include <cstddef>

#define B_    1024
#define L_    200
#define DIN_  256
#define DOUT_ 256
#define K_    8
#define M_    (B_ * L_)   // 204800

typedef __attribute__((ext_vector_type(8))) short bf16x8;
typedef __attribute__((ext_vector_type(4))) float f32x4;

__device__ __forceinline__ float bf2f(unsigned short u) {
  union { unsigned int i; float f; } w; w.i = ((unsigned int)u) << 16; return w.f;
}
__device__ __forceinline__ unsigned short f2bf(float f) {
  union { float f; unsigned int i; } w; w.f = f;
  unsigned int x = w.i;
  return (unsigned short)((x + 0x7fffu + ((x >> 16) & 1u)) >> 16);
}

// ---------------- kernel 0: split W into W^T_hi/mid/lo bf16 (n-major, contiguous k)
__global__ __launch_bounds__(256)
void wt_prep(const float* __restrict__ W, unsigned short* __restrict__ Wh,
             unsigned short* __restrict__ Wm, unsigned short* __restrict__ Wl)
{
  const int k = blockIdx.x;    // 256
  const int n = threadIdx.x;   // 256
  float x = W[k * DOUT_ + n];
  unsigned short h = f2bf(x);
  float r = x - bf2f(h);
  unsigned short m = f2bf(r);
  float r2 = r - bf2f(m);
  unsigned short l = f2bf(r2);
  Wh[n * DIN_ + k] = h;
  Wm[n * DIN_ + k] = m;
  Wl[n * DIN_ + k] = l;
}

// ---------------- kernel 1: mapped = A @ W via bf16x3-split MFMA (fp32-grade accuracy)
// No LDS: A frags converted in-register from global fp32; B frags direct 16B loads
// from precomputed W^T (L2-resident). Wave owns 32 rows x 256 cols; block = 128 rows.
__global__ __launch_bounds__(256, 2)
void gemm_mapped(const float* __restrict__ A,
                 const unsigned short* __restrict__ Wh,
                 const unsigned short* __restrict__ Wm,
                 const unsigned short* __restrict__ Wl,
                 float* __restrict__ C)
{
  const int t    = threadIdx.x;
  const int wave = t >> 6;
  const int lane = t & 63;
  const int quad = lane >> 4;
  const int lr   = lane & 15;
  const int m0   = blockIdx.x * 128 + wave * 32;

  f32x4 acc[2][16];
  #pragma unroll
  for (int mt = 0; mt < 2; ++mt)
    #pragma unroll
    for (int nt = 0; nt < 16; ++nt)
      acc[mt][nt] = (f32x4){0.f, 0.f, 0.f, 0.f};

  for (int k0 = 0; k0 < DIN_; k0 += 32) {
    const int kq = k0 + quad * 8;
    bf16x8 ah[2], am[2], al[2];
    #pragma unroll
    for (int mt = 0; mt < 2; ++mt) {
      const float* ap = A + (size_t)(m0 + mt * 16 + lr) * DIN_ + kq;
      float4 f0 = *(const float4*)ap;
      float4 f1 = *(const float4*)(ap + 4);
      float xs[8] = {f0.x, f0.y, f0.z, f0.w, f1.x, f1.y, f1.z, f1.w};
      #pragma unroll
      for (int j = 0; j < 8; ++j) {
        unsigned short h = f2bf(xs[j]);
        float r = xs[j] - bf2f(h);
        unsigned short mm = f2bf(r);
        float r2 = r - bf2f(mm);
        unsigned short ll = f2bf(r2);
        ah[mt][j] = (short)h; am[mt][j] = (short)mm; al[mt][j] = (short)ll;
      }
    }
    #pragma unroll
    for (int nt = 0; nt < 16; ++nt) {
      const size_t boff = (size_t)(nt * 16 + lr) * DIN_ + kq;
      bf16x8 bh = *(const bf16x8*)(Wh + boff);
      bf16x8 bm = *(const bf16x8*)(Wm + boff);
      bf16x8 bl = *(const bf16x8*)(Wl + boff);
      #pragma unroll
      for (int mt = 0; mt < 2; ++mt) {
        f32x4 c = acc[mt][nt];
        c = __builtin_amdgcn_mfma_f32_16x16x32_bf16(ah[mt], bh, c, 0, 0, 0);
        c = __builtin_amdgcn_mfma_f32_16x16x32_bf16(ah[mt], bm, c, 0, 0, 0);
        c = __builtin_amdgcn_mfma_f32_16x16x32_bf16(am[mt], bh, c, 0, 0, 0);
        c = __builtin_amdgcn_mfma_f32_16x16x32_bf16(ah[mt], bl, c, 0, 0, 0);
        c = __builtin_amdgcn_mfma_f32_16x16x32_bf16(am[mt], bm, c, 0, 0, 0);
        c = __builtin_amdgcn_mfma_f32_16x16x32_bf16(al[mt], bh, c, 0, 0, 0);
        acc[mt][nt] = c;
      }
    }
  }
  // C/D layout: row = quad*4 + reg, col = lr (within each 16x16 tile)
  #pragma unroll
  for (int mt = 0; mt < 2; ++mt)
    #pragma unroll
    for (int nt = 0; nt < 16; ++nt)
      #pragma unroll
      for (int r = 0; r < 4; ++r) {
        int row = m0 + mt * 16 + quad * 4 + r;
        C[(size_t)row * DOUT_ + nt * 16 + lr] = acc[mt][nt][r];
      }
}

// ---------------- kernel 2: per-b fused masked-softmax + Z + squash (wave-shuffle)
__global__ __launch_bounds__(256)
void z_kernel(const float* __restrict__ mapped, const float* __restrict__ logits,
              const int* __restrict__ seq_len, float* __restrict__ caps)
{
  const int b    = blockIdx.x;
  const int t    = threadIdx.x;
  const int lane = t & 63;
  const int wave = t >> 6;
  const int len  = seq_len[b];          // 1..200
  __shared__ float w[K_][204];          // 204: float4-aligned rows, zero-padded tail
  __shared__ float part[K_][4];

  // softmax: wave w handles capsules 2w, 2w+1 — shuffle reductions, no barriers
  #pragma unroll
  for (int kk = 0; kk < 2; ++kk) {
    const int k = wave * 2 + kk;
    float v[4];
    float mx = -3.4028235e38f;
    #pragma unroll
    for (int i = 0; i < 4; ++i) {
      int l = lane + 64 * i;
      v[i] = (l < len) ? logits[k * L_ + l] : -3.4028235e38f;
      mx = fmaxf(mx, v[i]);
    }
    #pragma unroll
    for (int s = 1; s < 64; s <<= 1) mx = fmaxf(mx, __shfl_xor(mx, s, 64));
    float e[4]; float sum = 0.f;
    #pragma unroll
    for (int i = 0; i < 4; ++i) {
      int l = lane + 64 * i;
      e[i] = (l < len) ? __expf(v[i] - mx) : 0.f;
      sum += e[i];
    }
    #pragma unroll
    for (int s = 1; s < 64; s <<= 1) sum += __shfl_xor(sum, s, 64);
    float inv = 1.f / sum;
    #pragma unroll
    for (int i = 0; i < 4; ++i) {
      int l = lane + 64 * i;
      if (l < 204) w[k][l] = e[i] * inv;   // exactly 0 for l >= len
    }
  }
  __syncthreads();

  // Z: thread t = output channel; weights are 0 beyond len so round len up to x4
  float acc[K_];
  #pragma unroll
  for (int k = 0; k < K_; ++k) acc[k] = 0.f;
  const float* mp = mapped + (size_t)b * L_ * DOUT_ + t;
  const int lceil = (len + 3) & ~3;      // <= 200
  for (int l = 0; l < lceil; l += 4) {
    float m0v = mp[(size_t)(l + 0) * DOUT_];
    float m1v = mp[(size_t)(l + 1) * DOUT_];
    float m2v = mp[(size_t)(l + 2) * DOUT_];
    float m3v = mp[(size_t)(l + 3) * DOUT_];
    #pragma unroll
    for (int k = 0; k < K_; ++k) {
      float4 wv = *(const float4*)&w[k][l];
      acc[k] += wv.x * m0v + wv.y * m1v + wv.z * m2v + wv.w * m3v;
    }
  }

  // squash: wave-shuffle partial norms, one LDS combine
  #pragma unroll
  for (int k = 0; k < K_; ++k) {
    float sq = acc[k] * acc[k];
    #pragma unroll
    for (int s = 1; s < 64; s <<= 1) sq += __shfl_xor(sq, s, 64);
    if (lane == 0) part[k][wave] = sq;
  }
  __syncthreads();
  #pragma unroll
  for (int k = 0; k < K_; ++k) {
    float sq = part[k][0] + part[k][1] + part[k][2] + part[k][3];
    float scale = sq / ((1.f + sq) * sqrtf(sq + 1e-8f));
    caps[((size_t)b * K_ + k) * DOUT_ + t] = scale * acc[k];
  }
}

// ---------------- kernel 3: delta partials (fp32 — precision-critical path)
#define LTILE 32
#define DSTR  260

__global__ __launch_bounds__(256)
void delta_kernel(const float* __restrict__ mapped, const float* __restrict__ caps,
                  float* __restrict__ partials)
{
  const int lt = blockIdx.x;   // 0..6
  const int bc = blockIdx.y;   // 0..63
  const int t  = threadIdx.x;
  __shared__ float capS[K_ * DSTR];      // capsule[k][o]
  __shared__ float mtS[LTILE * DSTR];    // mapped l-tile [l][o]

  const int ox   = t & 15;
  const int grp  = t >> 4;
  const int kp   = grp & 1;
  const int lgrp = grp >> 1;
  const int l0   = lt * LTILE;

  float acc[4][4];
  #pragma unroll
  for (int i = 0; i < 4; ++i)
    #pragma unroll
    for (int j = 0; j < 4; ++j) acc[i][j] = 0.f;

  for (int bi = 0; bi < 16; ++bi) {
    const int b = bc * 16 + bi;
    const float* cp = caps + (size_t)b * (K_ * DOUT_);
    #pragma unroll
    for (int r = 0; r < 2; ++r) {
      int e = r * 1024 + t * 4;
      int k = e >> 8, o = e & 255;
      *(float4*)&capS[k * DSTR + o] = *(const float4*)&cp[e];
    }
    const float* mpb = mapped + (size_t)b * (L_ * DOUT_);
    #pragma unroll
    for (int r = 0; r < 8; ++r) {
      int e = r * 1024 + t * 4;
      int ll = e >> 8, o = e & 255;
      int gl = l0 + ll;
      float4 v;
      if (gl < L_) v = *(const float4*)(mpb + (size_t)gl * DOUT_ + o);
      else         v = make_float4(0.f, 0.f, 0.f, 0.f);
      *(float4*)&mtS[ll * DSTR + o] = v;
    }
    __syncthreads();
    #pragma unroll
    for (int i = 0; i < 4; ++i) {
      const int o = ox * 4 + 64 * i;
      float4 c0 = *(const float4*)&capS[(kp * 4 + 0) * DSTR + o];
      float4 c1 = *(const float4*)&capS[(kp * 4 + 1) * DSTR + o];
      float4 c2 = *(const float4*)&capS[(kp * 4 + 2) * DSTR + o];
      float4 c3 = *(const float4*)&capS[(kp * 4 + 3) * DSTR + o];
      #pragma unroll
      for (int jl = 0; jl < 4; ++jl) {
        float4 m = *(const float4*)&mtS[(lgrp * 4 + jl) * DSTR + o];
        acc[0][jl] += c0.x * m.x + c0.y * m.y + c0.z * m.z + c0.w * m.w;
        acc[1][jl] += c1.x * m.x + c1.y * m.y + c1.z * m.z + c1.w * m.w;
        acc[2][jl] += c2.x * m.x + c2.y * m.y + c2.z * m.z + c2.w * m.w;
        acc[3][jl] += c3.x * m.x + c3.y * m.y + c3.z * m.z + c3.w * m.w;
      }
    }
    __syncthreads();
  }
  #pragma unroll
  for (int ki = 0; ki < 4; ++ki)
    #pragma unroll
    for (int jl = 0; jl < 4; ++jl) {
      float v = acc[ki][jl];
      v += __shfl_xor(v, 1, 64);
      v += __shfl_xor(v, 2, 64);
      v += __shfl_xor(v, 4, 64);
      v += __shfl_xor(v, 8, 64);
      if (ox == 0) {
        int k = kp * 4 + ki;
        int gl = l0 + lgrp * 4 + jl;
        if (gl < L_) partials[((size_t)bc * K_ + k) * L_ + gl] = v;
      }
    }
}

// ---------------- small kernels
__global__ __launch_bounds__(256)
void init_logits(const float* __restrict__ rlog, float* __restrict__ logits)
{
  int i = blockIdx.x * 256 + threadIdx.x;
  if (i < K_ * L_) logits[i] = rlog[i];
}

__global__ __launch_bounds__(256)
void reduce_kernel(const float* __restrict__ partials, float* __restrict__ logits)
{
  int i = blockIdx.x * 256 + threadIdx.x;
  if (i < K_ * L_) {
    float s = 0.f;
    #pragma unroll 4
    for (int bc = 0; bc < 64; ++bc) s += partials[bc * (K_ * L_) + i];
    logits[i] += s;
  }
}

extern "C" void kernel_launch(void* const* d_in, const int* in_sizes, int n_in,
                              void* d_out, int out_size, void* d_ws, size_t ws_size,
                              hipStream_t stream)
{
  const float* behav = (const float*)d_in[0];
  const int*   slen  = (const int*)d_in[1];
  const float* rlog  = (const float*)d_in[2];
  const float* W     = (const float*)d_in[3];
  float* caps = (float*)d_out;

  char* ws = (char*)d_ws;
  float* logitsW  = (float*)ws;                           // 6400 B
  float* partials = (float*)(ws + 8192);                  // 409600 B (ends 417792)
  unsigned short* Wh = (unsigned short*)(ws + 458752);    // 128 KiB each
  unsigned short* Wm = (unsigned short*)(ws + 589824);
  unsigned short* Wl = (unsigned short*)(ws + 720896);    // ends 851968 < 1 MiB
  float* mapped   = (float*)(ws + (1 << 20));             // 200 MiB fp32

  init_logits<<<dim3(7), 256, 0, stream>>>(rlog, logitsW);
  wt_prep<<<dim3(256), 256, 0, stream>>>(W, Wh, Wm, Wl);
  gemm_mapped<<<dim3(1600), 256, 0, stream>>>(behav, Wh, Wm, Wl, mapped);
  for (int it = 0; it < 3; ++it) {
    z_kernel<<<dim3(B_), 256, 0, stream>>>(mapped, logitsW, slen, caps);
    if (it < 2) {   // delta after the last iteration is dead code in the reference
      delta_kernel<<<dim3(7, 64), 256, 0, stream>>>(mapped, caps, partials);
      reduce_kernel<<<dim3(7), 256, 0, stream>>>(partials, logitsW);
    }
  }
}

// Round 3
// 761.559 us; speedup vs baseline: 1.2005x; 1.2005x over previous
//
#include <hip/hip_runtime.h>
#include <cstdint>
#include <cstddef>

#define B_    1024
#define L_    200
#define DIN_  256
#define DOUT_ 256
#define K_    8
#define M_    (B_ * L_)   // 204800

typedef __attribute__((ext_vector_type(8))) short bf16x8;
typedef __attribute__((ext_vector_type(4))) float f32x4;

__device__ __forceinline__ float bf2f(unsigned short u) {
  union { unsigned int i; float f; } w; w.i = ((unsigned int)u) << 16; return w.f;
}
__device__ __forceinline__ unsigned short f2bf(float f) {
  union { float f; unsigned int i; } w; w.f = f;
  unsigned int x = w.i;
  return (unsigned short)((x + 0x7fffu + ((x >> 16) & 1u)) >> 16);
}

// ---------------- kernel 0: split W into bf16 hi/mid/lo, stored in MFMA FRAGMENT ORDER.
// Wfrag[k0b][nt][lane][j]: lane = quad*16+lr encodes (n = nt*16+lr, k = k0b*32+quad*8+j).
// Hot-loop B load becomes base + lane*16B — fully coalesced (R2's was a 512B-stride gather).
__global__ __launch_bounds__(256)
void wt_prep(const float* __restrict__ W, unsigned short* __restrict__ Wh,
             unsigned short* __restrict__ Wm, unsigned short* __restrict__ Wl)
{
  const int k = blockIdx.x;    // 256
  const int n = threadIdx.x;   // 256
  float x = W[k * DOUT_ + n];
  unsigned short h = f2bf(x);
  float r = x - bf2f(h);
  unsigned short m = f2bf(r);
  float r2 = r - bf2f(m);
  unsigned short l = f2bf(r2);
  const int k0b = k >> 5, quad = (k >> 3) & 3, j = k & 7;
  const int nt = n >> 4, lr = n & 15;
  const size_t idx = ((((size_t)k0b * 16 + nt) * 64) + (quad * 16 + lr)) * 8 + j;
  Wh[idx] = h;
  Wm[idx] = m;
  Wl[idx] = l;
}

// ---------------- kernel 1: mapped = A @ W via bf16x3-split MFMA (numerics identical to R2)
__global__ __launch_bounds__(256, 2)
void gemm_mapped(const float* __restrict__ A,
                 const unsigned short* __restrict__ Wh,
                 const unsigned short* __restrict__ Wm,
                 const unsigned short* __restrict__ Wl,
                 float* __restrict__ C)
{
  const int t    = threadIdx.x;
  const int wave = t >> 6;
  const int lane = t & 63;
  const int quad = lane >> 4;
  const int lr   = lane & 15;
  const int m0   = blockIdx.x * 128 + wave * 32;

  f32x4 acc[2][16];
  #pragma unroll
  for (int mt = 0; mt < 2; ++mt)
    #pragma unroll
    for (int nt = 0; nt < 16; ++nt)
      acc[mt][nt] = (f32x4){0.f, 0.f, 0.f, 0.f};

  for (int k0 = 0; k0 < DIN_; k0 += 32) {
    const int kq  = k0 + quad * 8;
    const int k0b = k0 >> 5;
    bf16x8 ah[2], am[2], al[2];
    #pragma unroll
    for (int mt = 0; mt < 2; ++mt) {
      const float* ap = A + (size_t)(m0 + mt * 16 + lr) * DIN_ + kq;
      float4 f0 = *(const float4*)ap;
      float4 f1 = *(const float4*)(ap + 4);
      float xs[8] = {f0.x, f0.y, f0.z, f0.w, f1.x, f1.y, f1.z, f1.w};
      #pragma unroll
      for (int j = 0; j < 8; ++j) {
        unsigned short h = f2bf(xs[j]);
        float r = xs[j] - bf2f(h);
        unsigned short mm = f2bf(r);
        float r2 = r - bf2f(mm);
        unsigned short ll = f2bf(r2);
        ah[mt][j] = (short)h; am[mt][j] = (short)mm; al[mt][j] = (short)ll;
      }
    }
    #pragma unroll
    for (int nt = 0; nt < 16; ++nt) {
      // fragment-order: contiguous 16B per lane
      const size_t boff = (((size_t)k0b * 16 + nt) * 64 + lane) * 8;
      bf16x8 bh = *(const bf16x8*)(Wh + boff);
      bf16x8 bm = *(const bf16x8*)(Wm + boff);
      bf16x8 bl = *(const bf16x8*)(Wl + boff);
      #pragma unroll
      for (int mt = 0; mt < 2; ++mt) {
        f32x4 c = acc[mt][nt];
        c = __builtin_amdgcn_mfma_f32_16x16x32_bf16(ah[mt], bh, c, 0, 0, 0);
        c = __builtin_amdgcn_mfma_f32_16x16x32_bf16(ah[mt], bm, c, 0, 0, 0);
        c = __builtin_amdgcn_mfma_f32_16x16x32_bf16(am[mt], bh, c, 0, 0, 0);
        c = __builtin_amdgcn_mfma_f32_16x16x32_bf16(ah[mt], bl, c, 0, 0, 0);
        c = __builtin_amdgcn_mfma_f32_16x16x32_bf16(am[mt], bm, c, 0, 0, 0);
        c = __builtin_amdgcn_mfma_f32_16x16x32_bf16(al[mt], bh, c, 0, 0, 0);
        acc[mt][nt] = c;
      }
    }
  }
  // C/D layout: row = quad*4 + reg, col = lr (within each 16x16 tile)
  #pragma unroll
  for (int mt = 0; mt < 2; ++mt)
    #pragma unroll
    for (int nt = 0; nt < 16; ++nt)
      #pragma unroll
      for (int r = 0; r < 4; ++r) {
        int row = m0 + mt * 16 + quad * 4 + r;
        C[(size_t)row * DOUT_ + nt * 16 + lr] = acc[mt][nt][r];
      }
}

// ---------------- kernel 2: fused masked-softmax + Z + squash.
// One wave per b (4 b per block); lane owns 4 contiguous channels -> float4 loads.
// Each wave only touches w[wave] -> no __syncthreads anywhere.
__global__ __launch_bounds__(256)
void z_kernel(const float* __restrict__ mapped, const float* __restrict__ logits,
              const int* __restrict__ seq_len, float* __restrict__ caps)
{
  const int t    = threadIdx.x;
  const int lane = t & 63;
  const int wave = t >> 6;
  const int b    = blockIdx.x * 4 + wave;
  const int len  = seq_len[b];          // 1..200
  __shared__ float w[4][K_][204];       // per-wave weights, float4-aligned rows

  #pragma unroll
  for (int k = 0; k < K_; ++k) {
    float v[4];
    float mx = -3.4028235e38f;
    #pragma unroll
    for (int i = 0; i < 4; ++i) {
      int l = lane + 64 * i;
      v[i] = (l < len) ? logits[k * L_ + l] : -3.4028235e38f;
      mx = fmaxf(mx, v[i]);
    }
    #pragma unroll
    for (int s = 1; s < 64; s <<= 1) mx = fmaxf(mx, __shfl_xor(mx, s, 64));
    float e[4]; float sum = 0.f;
    #pragma unroll
    for (int i = 0; i < 4; ++i) {
      int l = lane + 64 * i;
      e[i] = (l < len) ? __expf(v[i] - mx) : 0.f;
      sum += e[i];
    }
    #pragma unroll
    for (int s = 1; s < 64; s <<= 1) sum += __shfl_xor(sum, s, 64);
    float inv = 1.f / sum;
    #pragma unroll
    for (int i = 0; i < 4; ++i) {
      int l = lane + 64 * i;
      if (l < 204) w[wave][k][l] = e[i] * inv;   // exactly 0 for l >= len
    }
  }
  // same-wave LDS RAW: hardware lgkmcnt handles it; no barrier needed.

  f32x4 acc[K_];
  #pragma unroll
  for (int k = 0; k < K_; ++k) acc[k] = (f32x4){0.f, 0.f, 0.f, 0.f};
  const float* mp = mapped + (size_t)b * L_ * DOUT_ + lane * 4;
  const int lceil = (len + 3) & ~3;     // <= 200; weights are 0 beyond len
  for (int l = 0; l < lceil; l += 4) {
    float4 m0 = *(const float4*)(mp + (size_t)(l + 0) * DOUT_);
    float4 m1 = *(const float4*)(mp + (size_t)(l + 1) * DOUT_);
    float4 m2 = *(const float4*)(mp + (size_t)(l + 2) * DOUT_);
    float4 m3 = *(const float4*)(mp + (size_t)(l + 3) * DOUT_);
    #pragma unroll
    for (int k = 0; k < K_; ++k) {
      float4 wv = *(const float4*)&w[wave][k][l];
      f32x4 c = acc[k];
      c.x += wv.x * m0.x + wv.y * m1.x + wv.z * m2.x + wv.w * m3.x;
      c.y += wv.x * m0.y + wv.y * m1.y + wv.z * m2.y + wv.w * m3.y;
      c.z += wv.x * m0.z + wv.y * m1.z + wv.z * m2.z + wv.w * m3.z;
      c.w += wv.x * m0.w + wv.y * m1.w + wv.z * m2.w + wv.w * m3.w;
      acc[k] = c;
    }
  }

  #pragma unroll
  for (int k = 0; k < K_; ++k) {
    float sq = acc[k].x * acc[k].x + acc[k].y * acc[k].y
             + acc[k].z * acc[k].z + acc[k].w * acc[k].w;
    #pragma unroll
    for (int s = 1; s < 64; s <<= 1) sq += __shfl_xor(sq, s, 64);
    float scale = sq / ((1.f + sq) * sqrtf(sq + 1e-8f));
    float4 o;
    o.x = scale * acc[k].x; o.y = scale * acc[k].y;
    o.z = scale * acc[k].z; o.w = scale * acc[k].w;
    *(float4*)&caps[((size_t)b * K_ + k) * DOUT_ + lane * 4] = o;
  }
}

// ---------------- kernel 3: delta partials (fp32 — precision-critical path)
#define LTILE 32
#define DSTR  260

__global__ __launch_bounds__(256)
void delta_kernel(const float* __restrict__ mapped, const float* __restrict__ caps,
                  float* __restrict__ partials)
{
  const int lt = blockIdx.x;   // 0..6
  const int bc = blockIdx.y;   // 0..63
  const int t  = threadIdx.x;
  __shared__ float capS[K_ * DSTR];      // capsule[k][o]
  __shared__ float mtS[LTILE * DSTR];    // mapped l-tile [l][o]

  const int ox   = t & 15;
  const int grp  = t >> 4;
  const int kp   = grp & 1;
  const int lgrp = grp >> 1;
  const int l0   = lt * LTILE;

  float acc[4][4];
  #pragma unroll
  for (int i = 0; i < 4; ++i)
    #pragma unroll
    for (int j = 0; j < 4; ++j) acc[i][j] = 0.f;

  for (int bi = 0; bi < 16; ++bi) {
    const int b = bc * 16 + bi;
    const float* cp = caps + (size_t)b * (K_ * DOUT_);
    #pragma unroll
    for (int r = 0; r < 2; ++r) {
      int e = r * 1024 + t * 4;
      int k = e >> 8, o = e & 255;
      *(float4*)&capS[k * DSTR + o] = *(const float4*)&cp[e];
    }
    const float* mpb = mapped + (size_t)b * (L_ * DOUT_);
    #pragma unroll
    for (int r = 0; r < 8; ++r) {
      int e = r * 1024 + t * 4;
      int ll = e >> 8, o = e & 255;
      int gl = l0 + ll;
      float4 v;
      if (gl < L_) v = *(const float4*)(mpb + (size_t)gl * DOUT_ + o);
      else         v = make_float4(0.f, 0.f, 0.f, 0.f);
      *(float4*)&mtS[ll * DSTR + o] = v;
    }
    __syncthreads();
    #pragma unroll
    for (int i = 0; i < 4; ++i) {
      const int o = ox * 4 + 64 * i;
      float4 c0 = *(const float4*)&capS[(kp * 4 + 0) * DSTR + o];
      float4 c1 = *(const float4*)&capS[(kp * 4 + 1) * DSTR + o];
      float4 c2 = *(const float4*)&capS[(kp * 4 + 2) * DSTR + o];
      float4 c3 = *(const float4*)&capS[(kp * 4 + 3) * DSTR + o];
      #pragma unroll
      for (int jl = 0; jl < 4; ++jl) {
        float4 m = *(const float4*)&mtS[(lgrp * 4 + jl) * DSTR + o];
        acc[0][jl] += c0.x * m.x + c0.y * m.y + c0.z * m.z + c0.w * m.w;
        acc[1][jl] += c1.x * m.x + c1.y * m.y + c1.z * m.z + c1.w * m.w;
        acc[2][jl] += c2.x * m.x + c2.y * m.y + c2.z * m.z + c2.w * m.w;
        acc[3][jl] += c3.x * m.x + c3.y * m.y + c3.z * m.z + c3.w * m.w;
      }
    }
    __syncthreads();
  }
  #pragma unroll
  for (int ki = 0; ki < 4; ++ki)
    #pragma unroll
    for (int jl = 0; jl < 4; ++jl) {
      float v = acc[ki][jl];
      v += __shfl_xor(v, 1, 64);
      v += __shfl_xor(v, 2, 64);
      v += __shfl_xor(v, 4, 64);
      v += __shfl_xor(v, 8, 64);
      if (ox == 0) {
        int k = kp * 4 + ki;
        int gl = l0 + lgrp * 4 + jl;
        if (gl < L_) partials[((size_t)bc * K_ + k) * L_ + gl] = v;
      }
    }
}

// ---------------- small kernels
__global__ __launch_bounds__(256)
void init_logits(const float* __restrict__ rlog, float* __restrict__ logits)
{
  int i = blockIdx.x * 256 + threadIdx.x;
  if (i < K_ * L_) logits[i] = rlog[i];
}

__global__ __launch_bounds__(256)
void reduce_kernel(const float* __restrict__ partials, float* __restrict__ logits)
{
  int i = blockIdx.x * 256 + threadIdx.x;
  if (i < K_ * L_) {
    float s = 0.f;
    #pragma unroll 4
    for (int bc = 0; bc < 64; ++bc) s += partials[bc * (K_ * L_) + i];
    logits[i] += s;
  }
}

extern "C" void kernel_launch(void* const* d_in, const int* in_sizes, int n_in,
                              void* d_out, int out_size, void* d_ws, size_t ws_size,
                              hipStream_t stream)
{
  const float* behav = (const float*)d_in[0];
  const int*   slen  = (const int*)d_in[1];
  const float* rlog  = (const float*)d_in[2];
  const float* W     = (const float*)d_in[3];
  float* caps = (float*)d_out;

  char* ws = (char*)d_ws;
  float* logitsW  = (float*)ws;                           // 6400 B
  float* partials = (float*)(ws + 8192);                  // 409600 B (ends 417792)
  unsigned short* Wh = (unsigned short*)(ws + 458752);    // 128 KiB each
  unsigned short* Wm = (unsigned short*)(ws + 589824);
  unsigned short* Wl = (unsigned short*)(ws + 720896);    // ends 851968 < 1 MiB
  float* mapped   = (float*)(ws + (1 << 20));             // 200 MiB fp32

  init_logits<<<dim3(7), 256, 0, stream>>>(rlog, logitsW);
  wt_prep<<<dim3(256), 256, 0, stream>>>(W, Wh, Wm, Wl);
  gemm_mapped<<<dim3(1600), 256, 0, stream>>>(behav, Wh, Wm, Wl, mapped);
  for (int it = 0; it < 3; ++it) {
    z_kernel<<<dim3(B_ / 4), 256, 0, stream>>>(mapped, logitsW, slen, caps);
    if (it < 2) {   // delta after the last iteration is dead code in the reference
      delta_kernel<<<dim3(7, 64), 256, 0, stream>>>(mapped, caps, partials);
      reduce_kernel<<<dim3(7), 256, 0, stream>>>(partials, logitsW);
    }
  }
}

// Round 4
// 635.422 us; speedup vs baseline: 1.4388x; 1.1985x over previous
//
#include <hip/hip_runtime.h>
#include <cstdint>
#include <cstddef>

#define B_    1024
#define L_    200
#define DIN_  256
#define DOUT_ 256
#define K_    8
#define M_    (B_ * L_)   // 204800

typedef __attribute__((ext_vector_type(8))) short bf16x8;
typedef __attribute__((ext_vector_type(4))) float f32x4;

__device__ __forceinline__ float bf2f(unsigned short u) {
  union { unsigned int i; float f; } w; w.i = ((unsigned int)u) << 16; return w.f;
}
__device__ __forceinline__ unsigned short f2bf(float f) {
  union { float f; unsigned int i; } w; w.f = f;
  unsigned int x = w.i;
  return (unsigned short)((x + 0x7fffu + ((x >> 16) & 1u)) >> 16);
}

// ---------------- kernel 0: split W into bf16 hi/mid/lo in MFMA FRAGMENT ORDER.
// Wfrag[k0b][nt][lane][j]: lane = quad*16+lr encodes (n = nt*16+lr, k = k0b*32+quad*8+j).
__global__ __launch_bounds__(256)
void wt_prep(const float* __restrict__ W, unsigned short* __restrict__ Wh,
             unsigned short* __restrict__ Wm, unsigned short* __restrict__ Wl)
{
  const int k = blockIdx.x;    // 256
  const int n = threadIdx.x;   // 256
  float x = W[k * DOUT_ + n];
  unsigned short h = f2bf(x);
  float r = x - bf2f(h);
  unsigned short m = f2bf(r);
  float r2 = r - bf2f(m);
  unsigned short l = f2bf(r2);
  const int k0b = k >> 5, quad = (k >> 3) & 3, j = k & 7;
  const int nt = n >> 4, lr = n & 15;
  const size_t idx = ((((size_t)k0b * 16 + nt) * 64) + (quad * 16 + lr)) * 8 + j;
  Wh[idx] = h;
  Wm[idx] = m;
  Wl[idx] = l;
}

// ---------------- kernel 1: mapped = A @ W via bf16x3-split MFMA, software-pipelined.
// 4-slot rolling B prefetch (~174cyc coverage); A raw loads prefetched one k0 ahead
// so the split-convert VALU overlaps load latency. Per-acc MFMA order identical to R3.
__global__ __launch_bounds__(256, 2)
void gemm_mapped(const float* __restrict__ A,
                 const unsigned short* __restrict__ Wh,
                 const unsigned short* __restrict__ Wm,
                 const unsigned short* __restrict__ Wl,
                 float* __restrict__ C)
{
  const int t    = threadIdx.x;
  const int wave = t >> 6;
  const int lane = t & 63;
  const int quad = lane >> 4;
  const int lr   = lane & 15;
  const int m0   = blockIdx.x * 128 + wave * 32;

  f32x4 acc[2][16];
  #pragma unroll
  for (int mt = 0; mt < 2; ++mt)
    #pragma unroll
    for (int nt = 0; nt < 16; ++nt)
      acc[mt][nt] = (f32x4){0.f, 0.f, 0.f, 0.f};

  bf16x8 Bh[4], Bm[4], Bl[4];
  bf16x8 ah[2], am[2], al[2];
  float4 Af[2][2];

#define BLOAD(K0B, NT, S) do { \
    const size_t _off = (((size_t)(K0B) * 16 + (NT)) * 64 + lane) * 8; \
    Bh[S] = *(const bf16x8*)(Wh + _off); \
    Bm[S] = *(const bf16x8*)(Wm + _off); \
    Bl[S] = *(const bf16x8*)(Wl + _off); \
  } while (0)

  const float* ap0 = A + (size_t)(m0 + lr) * DIN_ + quad * 8;
  const float* ap1 = A + (size_t)(m0 + 16 + lr) * DIN_ + quad * 8;

  // prologue: A raw for k0b=0; B slots 0..3 for k0b=0
  Af[0][0] = *(const float4*)(ap0);
  Af[0][1] = *(const float4*)(ap0 + 4);
  Af[1][0] = *(const float4*)(ap1);
  Af[1][1] = *(const float4*)(ap1 + 4);
  BLOAD(0, 0, 0); BLOAD(0, 1, 1); BLOAD(0, 2, 2); BLOAD(0, 3, 3);

  for (int k0b = 0; k0b < 8; ++k0b) {
    // convert prefetched A to bf16x3 fragments (overlaps in-flight B loads)
    #pragma unroll
    for (int mt = 0; mt < 2; ++mt) {
      float xs[8] = {Af[mt][0].x, Af[mt][0].y, Af[mt][0].z, Af[mt][0].w,
                     Af[mt][1].x, Af[mt][1].y, Af[mt][1].z, Af[mt][1].w};
      #pragma unroll
      for (int j = 0; j < 8; ++j) {
        unsigned short h = f2bf(xs[j]);
        float r = xs[j] - bf2f(h);
        unsigned short mm = f2bf(r);
        float r2 = r - bf2f(mm);
        unsigned short ll = f2bf(r2);
        ah[mt][j] = (short)h; am[mt][j] = (short)mm; al[mt][j] = (short)ll;
      }
    }
    // issue next k0's A raw loads (in flight through the whole nt loop)
    if (k0b < 7) {
      const int ko = (k0b + 1) * 32;
      Af[0][0] = *(const float4*)(ap0 + ko);
      Af[0][1] = *(const float4*)(ap0 + ko + 4);
      Af[1][0] = *(const float4*)(ap1 + ko);
      Af[1][1] = *(const float4*)(ap1 + ko + 4);
    }

#define GROUP(NT, S) do { \
    f32x4 c0 = acc[0][NT], c1 = acc[1][NT]; \
    c0 = __builtin_amdgcn_mfma_f32_16x16x32_bf16(ah[0], Bh[S], c0, 0, 0, 0); \
    c1 = __builtin_amdgcn_mfma_f32_16x16x32_bf16(ah[1], Bh[S], c1, 0, 0, 0); \
    c0 = __builtin_amdgcn_mfma_f32_16x16x32_bf16(ah[0], Bm[S], c0, 0, 0, 0); \
    c1 = __builtin_amdgcn_mfma_f32_16x16x32_bf16(ah[1], Bm[S], c1, 0, 0, 0); \
    c0 = __builtin_amdgcn_mfma_f32_16x16x32_bf16(am[0], Bh[S], c0, 0, 0, 0); \
    c1 = __builtin_amdgcn_mfma_f32_16x16x32_bf16(am[1], Bh[S], c1, 0, 0, 0); \
    c0 = __builtin_amdgcn_mfma_f32_16x16x32_bf16(ah[0], Bl[S], c0, 0, 0, 0); \
    c1 = __builtin_amdgcn_mfma_f32_16x16x32_bf16(ah[1], Bl[S], c1, 0, 0, 0); \
    c0 = __builtin_amdgcn_mfma_f32_16x16x32_bf16(am[0], Bm[S], c0, 0, 0, 0); \
    c1 = __builtin_amdgcn_mfma_f32_16x16x32_bf16(am[1], Bm[S], c1, 0, 0, 0); \
    c0 = __builtin_amdgcn_mfma_f32_16x16x32_bf16(al[0], Bh[S], c0, 0, 0, 0); \
    c1 = __builtin_amdgcn_mfma_f32_16x16x32_bf16(al[1], Bh[S], c1, 0, 0, 0); \
    acc[0][NT] = c0; acc[1][NT] = c1; \
  } while (0)

    // nt loop: MFMAs on slot nt&3, then prefetch nt+4 into the freed slot
    GROUP(0, 0);  BLOAD(k0b, 4, 0);
    GROUP(1, 1);  BLOAD(k0b, 5, 1);
    GROUP(2, 2);  BLOAD(k0b, 6, 2);
    GROUP(3, 3);  BLOAD(k0b, 7, 3);
    GROUP(4, 0);  BLOAD(k0b, 8, 0);
    GROUP(5, 1);  BLOAD(k0b, 9, 1);
    GROUP(6, 2);  BLOAD(k0b, 10, 2);
    GROUP(7, 3);  BLOAD(k0b, 11, 3);
    GROUP(8, 0);  BLOAD(k0b, 12, 0);
    GROUP(9, 1);  BLOAD(k0b, 13, 1);
    GROUP(10, 2); BLOAD(k0b, 14, 2);
    GROUP(11, 3); BLOAD(k0b, 15, 3);
    GROUP(12, 0);
    GROUP(13, 1);
    GROUP(14, 2);
    GROUP(15, 3);
    if (k0b < 7) {
      BLOAD(k0b + 1, 0, 0); BLOAD(k0b + 1, 1, 1);
      BLOAD(k0b + 1, 2, 2); BLOAD(k0b + 1, 3, 3);
    }
#undef GROUP
  }
#undef BLOAD

  // C/D layout: row = quad*4 + reg, col = lr (within each 16x16 tile)
  #pragma unroll
  for (int mt = 0; mt < 2; ++mt)
    #pragma unroll
    for (int nt = 0; nt < 16; ++nt)
      #pragma unroll
      for (int r = 0; r < 4; ++r) {
        int row = m0 + mt * 16 + quad * 4 + r;
        C[(size_t)row * DOUT_ + nt * 16 + lr] = acc[mt][nt][r];
      }
}

// ---------------- kernel 2: fused masked-softmax + Z + squash (unchanged from R3)
__global__ __launch_bounds__(256)
void z_kernel(const float* __restrict__ mapped, const float* __restrict__ logits,
              const int* __restrict__ seq_len, float* __restrict__ caps)
{
  const int t    = threadIdx.x;
  const int lane = t & 63;
  const int wave = t >> 6;
  const int b    = blockIdx.x * 4 + wave;
  const int len  = seq_len[b];          // 1..200
  __shared__ float w[4][K_][204];

  #pragma unroll
  for (int k = 0; k < K_; ++k) {
    float v[4];
    float mx = -3.4028235e38f;
    #pragma unroll
    for (int i = 0; i < 4; ++i) {
      int l = lane + 64 * i;
      v[i] = (l < len) ? logits[k * L_ + l] : -3.4028235e38f;
      mx = fmaxf(mx, v[i]);
    }
    #pragma unroll
    for (int s = 1; s < 64; s <<= 1) mx = fmaxf(mx, __shfl_xor(mx, s, 64));
    float e[4]; float sum = 0.f;
    #pragma unroll
    for (int i = 0; i < 4; ++i) {
      int l = lane + 64 * i;
      e[i] = (l < len) ? __expf(v[i] - mx) : 0.f;
      sum += e[i];
    }
    #pragma unroll
    for (int s = 1; s < 64; s <<= 1) sum += __shfl_xor(sum, s, 64);
    float inv = 1.f / sum;
    #pragma unroll
    for (int i = 0; i < 4; ++i) {
      int l = lane + 64 * i;
      if (l < 204) w[wave][k][l] = e[i] * inv;   // exactly 0 for l >= len
    }
  }

  f32x4 acc[K_];
  #pragma unroll
  for (int k = 0; k < K_; ++k) acc[k] = (f32x4){0.f, 0.f, 0.f, 0.f};
  const float* mp = mapped + (size_t)b * L_ * DOUT_ + lane * 4;
  const int lceil = (len + 3) & ~3;
  for (int l = 0; l < lceil; l += 4) {
    float4 m0 = *(const float4*)(mp + (size_t)(l + 0) * DOUT_);
    float4 m1 = *(const float4*)(mp + (size_t)(l + 1) * DOUT_);
    float4 m2 = *(const float4*)(mp + (size_t)(l + 2) * DOUT_);
    float4 m3 = *(const float4*)(mp + (size_t)(l + 3) * DOUT_);
    #pragma unroll
    for (int k = 0; k < K_; ++k) {
      float4 wv = *(const float4*)&w[wave][k][l];
      f32x4 c = acc[k];
      c.x += wv.x * m0.x + wv.y * m1.x + wv.z * m2.x + wv.w * m3.x;
      c.y += wv.x * m0.y + wv.y * m1.y + wv.z * m2.y + wv.w * m3.y;
      c.z += wv.x * m0.z + wv.y * m1.z + wv.z * m2.z + wv.w * m3.z;
      c.w += wv.x * m0.w + wv.y * m1.w + wv.z * m2.w + wv.w * m3.w;
      acc[k] = c;
    }
  }

  #pragma unroll
  for (int k = 0; k < K_; ++k) {
    float sq = acc[k].x * acc[k].x + acc[k].y * acc[k].y
             + acc[k].z * acc[k].z + acc[k].w * acc[k].w;
    #pragma unroll
    for (int s = 1; s < 64; s <<= 1) sq += __shfl_xor(sq, s, 64);
    float scale = sq / ((1.f + sq) * sqrtf(sq + 1e-8f));
    float4 o;
    o.x = scale * acc[k].x; o.y = scale * acc[k].y;
    o.z = scale * acc[k].z; o.w = scale * acc[k].w;
    *(float4*)&caps[((size_t)b * K_ + k) * DOUT_ + lane * 4] = o;
  }
}

// ---------------- kernel 3: delta partials — LDS-free register-blocked rewrite.
// Wave owns 8 l x 16 b; lane owns 4 channels. caps is L2-resident (8 MB);
// mapped is read exactly once per call (coalesced float4). Deterministic partials.
__global__ __launch_bounds__(256)
void delta_kernel(const float* __restrict__ mapped, const float* __restrict__ caps,
                  float* __restrict__ partials)
{
  const int t    = threadIdx.x;
  const int lane = t & 63;
  const int wave = t >> 6;
  const int wid  = blockIdx.x * 4 + wave;   // 0..1599
  const int lc   = wid % 25;                // l-chunk: 8 l's
  const int bc   = wid / 25;                // b-chunk: 16 b's (0..63)
  const int l0   = lc * 8;
  const int o4   = lane * 4;

  const float* cb = caps   + (size_t)(bc * 16) * (K_ * DOUT_) + o4;
  const float* mb = mapped + ((size_t)(bc * 16) * L_ + l0) * DOUT_ + o4;

  float acc[K_][8];
  #pragma unroll
  for (int k = 0; k < K_; ++k)
    #pragma unroll
    for (int ll = 0; ll < 8; ++ll) acc[k][ll] = 0.f;

  float4 cA[K_], mA[8], cB[K_], mB[8];

#define LOADC(DST, BI) do { \
    const float* _p = cb + (size_t)(BI) * (K_ * DOUT_); \
    _Pragma("unroll") \
    for (int _k = 0; _k < K_; ++_k) DST[_k] = *(const float4*)(_p + _k * DOUT_); \
  } while (0)
#define LOADM(DST, BI) do { \
    const float* _p = mb + (size_t)(BI) * (L_ * DOUT_); \
    _Pragma("unroll") \
    for (int _l = 0; _l < 8; ++_l) DST[_l] = *(const float4*)(_p + _l * DOUT_); \
  } while (0)
#define COMPUTE(CC, MM) do { \
    _Pragma("unroll") \
    for (int _k = 0; _k < K_; ++_k) \
      _Pragma("unroll") \
      for (int _l = 0; _l < 8; ++_l) \
        acc[_k][_l] += CC[_k].x * MM[_l].x + CC[_k].y * MM[_l].y \
                     + CC[_k].z * MM[_l].z + CC[_k].w * MM[_l].w; \
  } while (0)

  LOADC(cA, 0); LOADM(mA, 0);
  for (int i = 0; i < 8; ++i) {           // 2 b per iteration, double-buffered
    LOADC(cB, 2 * i + 1); LOADM(mB, 2 * i + 1);
    COMPUTE(cA, mA);
    if (i < 7) { LOADC(cA, 2 * i + 2); LOADM(mA, 2 * i + 2); }
    COMPUTE(cB, mB);
  }
#undef LOADC
#undef LOADM
#undef COMPUTE

  // lane-reduce each (k,ll) over the 64 lanes (256 channels); lane k*8+ll keeps it
  float out = 0.f;
  #pragma unroll
  for (int k = 0; k < K_; ++k)
    #pragma unroll
    for (int ll = 0; ll < 8; ++ll) {
      float v = acc[k][ll];
      v += __shfl_xor(v, 1, 64);
      v += __shfl_xor(v, 2, 64);
      v += __shfl_xor(v, 4, 64);
      v += __shfl_xor(v, 8, 64);
      v += __shfl_xor(v, 16, 64);
      v += __shfl_xor(v, 32, 64);
      if (lane == k * 8 + ll) out = v;
    }
  partials[((size_t)bc * K_ + (lane >> 3)) * L_ + l0 + (lane & 7)] = out;
}

// ---------------- small kernels
__global__ __launch_bounds__(256)
void init_logits(const float* __restrict__ rlog, float* __restrict__ logits)
{
  int i = blockIdx.x * 256 + threadIdx.x;
  if (i < K_ * L_) logits[i] = rlog[i];
}

__global__ __launch_bounds__(256)
void reduce_kernel(const float* __restrict__ partials, float* __restrict__ logits)
{
  int i = blockIdx.x * 256 + threadIdx.x;
  if (i < K_ * L_) {
    float s = 0.f;
    #pragma unroll 4
    for (int bc = 0; bc < 64; ++bc) s += partials[bc * (K_ * L_) + i];
    logits[i] += s;
  }
}

extern "C" void kernel_launch(void* const* d_in, const int* in_sizes, int n_in,
                              void* d_out, int out_size, void* d_ws, size_t ws_size,
                              hipStream_t stream)
{
  const float* behav = (const float*)d_in[0];
  const int*   slen  = (const int*)d_in[1];
  const float* rlog  = (const float*)d_in[2];
  const float* W     = (const float*)d_in[3];
  float* caps = (float*)d_out;

  char* ws = (char*)d_ws;
  float* logitsW  = (float*)ws;                           // 6400 B
  float* partials = (float*)(ws + 8192);                  // 409600 B (ends 417792)
  unsigned short* Wh = (unsigned short*)(ws + 458752);    // 128 KiB each
  unsigned short* Wm = (unsigned short*)(ws + 589824);
  unsigned short* Wl = (unsigned short*)(ws + 720896);    // ends 851968 < 1 MiB
  float* mapped   = (float*)(ws + (1 << 20));             // 200 MiB fp32

  init_logits<<<dim3(7), 256, 0, stream>>>(rlog, logitsW);
  wt_prep<<<dim3(256), 256, 0, stream>>>(W, Wh, Wm, Wl);
  gemm_mapped<<<dim3(1600), 256, 0, stream>>>(behav, Wh, Wm, Wl, mapped);
  for (int it = 0; it < 3; ++it) {
    z_kernel<<<dim3(B_ / 4), 256, 0, stream>>>(mapped, logitsW, slen, caps);
    if (it < 2) {   // delta after the last iteration is dead code in the reference
      delta_kernel<<<dim3(400), 256, 0, stream>>>(mapped, caps, partials);
      reduce_kernel<<<dim3(7), 256, 0, stream>>>(partials, logitsW);
    }
  }
}